// Round 8
// baseline (220.093 us; speedup 1.0000x reference)
//
#include <hip/hip_runtime.h>

// get_fc_pix_discriminator_1x1_solo: fused 5-layer per-pixel MLP + BCE mean.
// B=4, C=19, H=256, W=512 -> 524288 px. dims 19->64->128->256->512->1.
// R8 (on R7's 288us base, occupancy stuck at 1 WG/CU):
//  (a) LDS shrunk to EXACTLY 65536 B (zs[] removed; final reduction reuses
//      sb0 bytes after the last barrier). 2x66048 = 132096 > 128KB pool was
//      a candidate occupancy limiter; 2x65536 fits even a 128KB pool.
//  (b) f32->bf16 packing via v_cvt_pk_bf16_f32 inline asm (1 inst / 2 vals
//      vs ~8 for the manual RNE bit-twiddle; compiler can't fuse the manual
//      form). Same RNE rounding -> bit-identical output.

#define HW_ 131072      // 256*512 = 2^17
#define NPIX 524288

using bf16x8 = __attribute__((ext_vector_type(8))) short;
using f32x4  = __attribute__((ext_vector_type(4))) float;

#define MFMA __builtin_amdgcn_mfma_f32_16x16x32_bf16

__device__ __forceinline__ unsigned short f2bf(float f) {
  unsigned u = __builtin_bit_cast(unsigned, f);
  u += 0x7FFFu + ((u >> 16) & 1u);   // round-to-nearest-even
  return (unsigned short)(u >> 16);
}

// sigma^-1: k-slot -> source feature index (within 32-chunks)
__device__ __forceinline__ int kinv(int k) {
  return ((k >> 5) << 5) + (((k >> 2) & 1) << 4) + (((k >> 3) & 3) << 2) + (k & 3);
}

// ---- weight bf16 pre-conversion into MFMA A-fragment order ----------------
// layer frag space: [ob][ks][lane][j];  o = ob*16+(lane&15),
// k = ks*32+(lane>>4)*8+j, feature f = PERM ? kinv(k) : k (0 if f>=K0).
// elem offset = ((ob*KS+ks)<<9) + lane*8  -> 1KB coalesced frag per wave.
#define OW1 0
#define OW2 2048
#define OW3 10240
#define OW4 43008
#define WTOT 174080

template <int K0, int KP, bool PERM>
__device__ __forceinline__ void conv_layer(const float* __restrict__ W,
                                           unsigned short* __restrict__ out,
                                           int i) {
  int r9 = i & 511;
  int lane = r9 >> 3, j = r9 & 7;
  int frag = i >> 9;               // = ob*KS + ks
  constexpr int KS = KP / 32;
  int ob = frag / KS, ks = frag - ob * KS;
  int o = ob * 16 + (lane & 15);
  int k = ks * 32 + ((lane >> 4) << 3) + j;
  int f = PERM ? kinv(k) : k;
  out[i] = f2bf(f < K0 ? W[o * K0 + f] : 0.f);
}

__global__ void wconv_kernel(const float* __restrict__ W1, const float* __restrict__ W2,
                             const float* __restrict__ W3, const float* __restrict__ W4,
                             unsigned short* __restrict__ wb) {
  int i = blockIdx.x * 256 + threadIdx.x;
  if (i < OW2) {
    conv_layer<19, 32, false>(W1, wb + OW1, i - OW1);
  } else if (i < OW3) {
    conv_layer<64, 64, true>(W2, wb + OW2, i - OW2);
  } else if (i < OW4) {
    conv_layer<128, 128, true>(W3, wb + OW3, i - OW3);
  } else if (i < WTOT) {
    conv_layer<256, 256, true>(W4, wb + OW4, i - OW4);
  }
}

__device__ __forceinline__ f32x4 leaky4(f32x4 v) {
  f32x4 r;
#pragma unroll
  for (int i = 0; i < 4; i++) r[i] = fmaxf(v[i], 0.2f * v[i]);
  return r;
}

// f32 pair -> packed bf16x2 (RNE), single HW instruction (no builtin; T12)
__device__ __forceinline__ unsigned cvtpk(float lo, float hi) {
  unsigned r;
  asm("v_cvt_pk_bf16_f32 %0, %1, %2" : "=v"(r) : "v"(lo), "v"(hi));
  return r;
}
__device__ __forceinline__ bf16x8 pack8(f32x4 e, f32x4 o) {
  union { unsigned u[4]; bf16x8 v; } r;
  r.u[0] = cvtpk(e[0], e[1]);
  r.u[1] = cvtpk(e[2], e[3]);
  r.u[2] = cvtpk(o[0], o[1]);
  r.u[3] = cvtpk(o[2], o[3]);
  return r.v;
}

// ---- async global -> LDS staging (16B/lane, identity layout) --------------
__device__ __forceinline__ void gl16(const unsigned char* g, unsigned char* l) {
  __builtin_amdgcn_global_load_lds(
      (const __attribute__((address_space(1))) unsigned int*)(const void*)g,
      (__attribute__((address_space(3))) unsigned int*)(void*)l, 16, 0, 0);
}
// NB 4KB blocks: global src per-lane (base + t*16), LDS dest wave-uniform
// (base + wave*1024); HW writes lane i at dest + i*16 -> identity copy.
template <int NB>
__device__ __forceinline__ void stage(const unsigned char* __restrict__ g,
                                      unsigned char* l, int t) {
  int wbase = (t >> 6) << 10;
  int lbase = (t & 63) << 4;
#pragma unroll
  for (int i = 0; i < NB; i++)
    gl16(g + i * 4096 + wbase + lbase, l + i * 4096 + wbase);
}

// frag read from LDS chunk: local frag lf, lane-linear 16B (conflict-free)
#define LDF(bufp, lf) (*(const bf16x8*)((bufp) + ((lf) << 10) + (lane << 4)))

__global__ __launch_bounds__(256) __attribute__((amdgpu_waves_per_eu(1, 2)))
void disc_lds(const float* __restrict__ x, const float* __restrict__ lbl,
              const unsigned short* __restrict__ wb,
              const float* __restrict__ b1, const float* __restrict__ b2,
              const float* __restrict__ b3, const float* __restrict__ b4,
              const float* __restrict__ W5f, const float* __restrict__ b5,
              float* __restrict__ out) {
  __shared__ __align__(16) unsigned char sb0[32768];
  __shared__ __align__(16) unsigned char sb1[32768];
  // total LDS = 65536 B exactly; final reduction reuses sb0's bytes.

  int t = threadIdx.x;
  int wave = t >> 6, lane = t & 63;
  int g = lane >> 4, li = lane & 15;
  long px0 = ((long)blockIdx.x * 4 + wave) * 64;
  int b = (int)(px0 >> 17);
  int hw0 = (int)(px0 & (HW_ - 1));
  const unsigned char* wb8 = (const unsigned char*)wb;

  // c0 = W1+W2 (20480 B) -> sb0
  stage<5>(wb8, sb0, t);
  __syncthreads();

  // c1 = W3 frags 0-31 -> sb1 (in flight across x-load + L1 + L2)
  stage<8>(wb8 + 20480, sb1, t);

  // ---- x -> B-frags (k = input channel c; c>=19 zero) ---------------------
  bf16x8 xb[4];
#pragma unroll
  for (int pb = 0; pb < 4; pb++) {
    const float* xp = x + (((long)b * 19) << 17) + hw0 + pb * 16 + li;
    bf16x8 v;
#pragma unroll
    for (int j = 0; j < 8; j++) {
      int c = 8 * g + j;
      float f = (c < 19) ? xp[(long)c << 17] : 0.f;
      v[j] = (short)f2bf(f);
    }
    xb[pb] = v;
  }

  // ---- L1: 19->64, frags 0..3 in sb0 --------------------------------------
  bf16x8 h1[4][2];
#pragma unroll
  for (int obp = 0; obp < 2; obp++) {
    bf16x8 fE = LDF(sb0, 2 * obp);
    bf16x8 fO = LDF(sb0, 2 * obp + 1);
    f32x4 bE = *(const f32x4*)(b1 + 32 * obp + 4 * g);
    f32x4 bO = *(const f32x4*)(b1 + 32 * obp + 16 + 4 * g);
#pragma unroll
    for (int pb = 0; pb < 4; pb++) {
      f32x4 aE = MFMA(fE, xb[pb], bE, 0, 0, 0);
      f32x4 aO = MFMA(fO, xb[pb], bO, 0, 0, 0);
      h1[pb][obp] = pack8(leaky4(aE), leaky4(aO));
    }
  }

  // ---- L2: 64->128, frags 4 + ob*2 + ks in sb0 ----------------------------
  bf16x8 h2[4][4];
#pragma unroll
  for (int obp = 0; obp < 4; obp++) {
    bf16x8 fE0 = LDF(sb0, 4 + 4 * obp);
    bf16x8 fE1 = LDF(sb0, 4 + 4 * obp + 1);
    bf16x8 fO0 = LDF(sb0, 4 + 4 * obp + 2);
    bf16x8 fO1 = LDF(sb0, 4 + 4 * obp + 3);
    f32x4 bE = *(const f32x4*)(b2 + 32 * obp + 4 * g);
    f32x4 bO = *(const f32x4*)(b2 + 32 * obp + 16 + 4 * g);
#pragma unroll
    for (int pb = 0; pb < 4; pb++) {
      f32x4 aE = MFMA(fE0, h1[pb][0], bE, 0, 0, 0);
      aE = MFMA(fE1, h1[pb][1], aE, 0, 0, 0);
      f32x4 aO = MFMA(fO0, h1[pb][0], bO, 0, 0, 0);
      aO = MFMA(fO1, h1[pb][1], aO, 0, 0, 0);
      h2[pb][obp] = pack8(leaky4(aE), leaky4(aO));
    }
  }
  __syncthreads();           // drains c1

  // c2 = W3 frags 32-63 -> sb0 (in flight across L3 half 0)
  stage<8>(wb8 + 53248, sb0, t);

  // ---- L3 half 0: obs 0-7 from sb1 ----------------------------------------
  bf16x8 h3[4][8];
#pragma unroll
  for (int obp = 0; obp < 4; obp++) {
    int lfE = (2 * obp) * 4, lfO = (2 * obp + 1) * 4;
    f32x4 bE = *(const f32x4*)(b3 + 32 * obp + 4 * g);
    f32x4 bO = *(const f32x4*)(b3 + 32 * obp + 16 + 4 * g);
    f32x4 aE[4], aO[4];
#pragma unroll
    for (int pb = 0; pb < 4; pb++) { aE[pb] = bE; aO[pb] = bO; }
#pragma unroll
    for (int ks = 0; ks < 4; ks++) {
      bf16x8 fE = LDF(sb1, lfE + ks);
      bf16x8 fO = LDF(sb1, lfO + ks);
#pragma unroll
      for (int pb = 0; pb < 4; pb++) {
        aE[pb] = MFMA(fE, h2[pb][ks], aE[pb], 0, 0, 0);
        aO[pb] = MFMA(fO, h2[pb][ks], aO[pb], 0, 0, 0);
      }
    }
#pragma unroll
    for (int pb = 0; pb < 4; pb++)
      h3[pb][obp] = pack8(leaky4(aE[pb]), leaky4(aO[pb]));
  }
  __syncthreads();           // drains c2

  // c3 = W4 frags 0-31 -> sb1 (in flight across L3 half 1)
  stage<8>(wb8 + 86016, sb1, t);

  // ---- L3 half 1: obs 8-15 from sb0 ---------------------------------------
#pragma unroll
  for (int obp = 4; obp < 8; obp++) {
    int lfE = (2 * obp) * 4 - 32, lfO = (2 * obp + 1) * 4 - 32;
    f32x4 bE = *(const f32x4*)(b3 + 32 * obp + 4 * g);
    f32x4 bO = *(const f32x4*)(b3 + 32 * obp + 16 + 4 * g);
    f32x4 aE[4], aO[4];
#pragma unroll
    for (int pb = 0; pb < 4; pb++) { aE[pb] = bE; aO[pb] = bO; }
#pragma unroll
    for (int ks = 0; ks < 4; ks++) {
      bf16x8 fE = LDF(sb0, lfE + ks);
      bf16x8 fO = LDF(sb0, lfO + ks);
#pragma unroll
      for (int pb = 0; pb < 4; pb++) {
        aE[pb] = MFMA(fE, h2[pb][ks], aE[pb], 0, 0, 0);
        aO[pb] = MFMA(fO, h2[pb][ks], aO[pb], 0, 0, 0);
      }
    }
#pragma unroll
    for (int pb = 0; pb < 4; pb++)
      h3[pb][obp] = pack8(leaky4(aE[pb]), leaky4(aO[pb]));
  }
  __syncthreads();           // drains c3

  // ---- L4+L5 fused: 8 chunks x 4 obs, LDS ping-pong with async prefetch ---
  f32x4 zp[4];
#pragma unroll
  for (int pb = 0; pb < 4; pb++) zp[pb] = f32x4{0.f, 0.f, 0.f, 0.f};

#pragma unroll 1
  for (int j = 0; j < 8; j++) {
    const unsigned char* cur = (j & 1) ? sb0 : sb1;
    unsigned char* nxt = (j & 1) ? sb1 : sb0;
    if (j < 7) stage<8>(wb8 + 86016 + (j + 1) * 32768, nxt, t);
    for (int oo = 0; oo < 4; oo++) {
      int ob = 4 * j + oo;
      f32x4 bv = *(const f32x4*)(b4 + 16 * ob + 4 * g);
      f32x4 w5v = *(const f32x4*)(W5f + 16 * ob + 4 * g);
      f32x4 a[4];
#pragma unroll
      for (int pb = 0; pb < 4; pb++) a[pb] = bv;
#pragma unroll
      for (int ks = 0; ks < 8; ks++) {
        bf16x8 f4 = LDF(cur, oo * 8 + ks);
#pragma unroll
        for (int pb = 0; pb < 4; pb++) a[pb] = MFMA(f4, h3[pb][ks], a[pb], 0, 0, 0);
      }
#pragma unroll
      for (int pb = 0; pb < 4; pb++) {
        f32x4 lv = leaky4(a[pb]);
#pragma unroll
        for (int i = 0; i < 4; i++) zp[pb][i] = fmaf(lv[i], w5v[i], zp[pb][i]);
      }
    }
    __syncthreads();   // all waves done reading cur; prefetch into nxt drained
  }

  // ---- z per pixel + BCE + reduction (reuse sb0 bytes for 4 floats) -------
  float zb[4];
#pragma unroll
  for (int pb = 0; pb < 4; pb++) {
    float s = zp[pb][0] + zp[pb][1] + zp[pb][2] + zp[pb][3];
    s += __shfl_xor(s, 16);
    s += __shfl_xor(s, 32);
    zb[pb] = s;  // full z for px (pb,li), replicated across g
  }
  float zsel = (g == 0) ? zb[0] : (g == 1) ? zb[1] : (g == 2) ? zb[2] : zb[3];
  float z = zsel + b5[0];
  float lab = lbl[px0 + lane];
  float w = fmaxf(z, 0.f) - z * lab + log1pf(expf(-fabsf(z)));
#pragma unroll
  for (int m = 1; m <= 32; m <<= 1) w += __shfl_xor(w, m);
  float* zsp = (float*)sb0;  // weights fully consumed after last barrier
  if (lane == 0) zsp[wave] = w;
  __syncthreads();
  if (t == 0)
    atomicAdd(out, (zsp[0] + zsp[1] + zsp[2] + zsp[3]) * (1.f / (float)NPIX));
}

// ---- fallback (ws too small): R5 register-chained kernel, direct gather ---
#define LDAG(dst, Wf, K0, KP, PERM, ob, ks)                                    \
  do {                                                                         \
    int o_ = (ob) * 16 + li;                                                   \
    for (int j_ = 0; j_ < 8; j_++) {                                           \
      int k_ = (ks) * 32 + (g << 3) + j_;                                      \
      int f_ = (PERM) ? kinv(k_) : k_;                                         \
      float v_ = f_ < (K0) ? (Wf)[o_ * (K0) + f_] : 0.f;                       \
      dst[j_] = (short)f2bf(v_);                                               \
    }                                                                          \
  } while (0)

__global__ __launch_bounds__(256, 1) void disc_fb(
    const float* __restrict__ x, const float* __restrict__ lbl,
    const float* __restrict__ W1f, const float* __restrict__ b1,
    const float* __restrict__ W2f, const float* __restrict__ b2,
    const float* __restrict__ W3f, const float* __restrict__ b3,
    const float* __restrict__ W4f, const float* __restrict__ b4,
    const float* __restrict__ W5f, const float* __restrict__ b5,
    float* __restrict__ out) {
  __shared__ float zs[4];
  int t = threadIdx.x;
  int wave = t >> 6, lane = t & 63;
  int g = lane >> 4, li = lane & 15;
  long px0 = ((long)blockIdx.x * 4 + wave) * 64;
  int b = (int)(px0 >> 17);
  int hw0 = (int)(px0 & (HW_ - 1));

  bf16x8 xb[4];
#pragma unroll
  for (int pb = 0; pb < 4; pb++) {
    const float* xp = x + (((long)b * 19) << 17) + hw0 + pb * 16 + li;
    bf16x8 v;
#pragma unroll
    for (int j = 0; j < 8; j++) {
      int c = 8 * g + j;
      float f = (c < 19) ? xp[(long)c << 17] : 0.f;
      v[j] = (short)f2bf(f);
    }
    xb[pb] = v;
  }

  bf16x8 h1[4][2];
#pragma unroll
  for (int obp = 0; obp < 2; obp++) {
    bf16x8 fE, fO;
    LDAG(fE, W1f, 19, 32, false, 2 * obp, 0);
    LDAG(fO, W1f, 19, 32, false, 2 * obp + 1, 0);
    f32x4 bE = *(const f32x4*)(b1 + 32 * obp + 4 * g);
    f32x4 bO = *(const f32x4*)(b1 + 32 * obp + 16 + 4 * g);
#pragma unroll
    for (int pb = 0; pb < 4; pb++) {
      f32x4 aE = MFMA(fE, xb[pb], bE, 0, 0, 0);
      f32x4 aO = MFMA(fO, xb[pb], bO, 0, 0, 0);
      h1[pb][obp] = pack8(leaky4(aE), leaky4(aO));
    }
  }

  bf16x8 h2[4][4];
#pragma unroll
  for (int obp = 0; obp < 4; obp++) {
    bf16x8 fE0, fE1, fO0, fO1;
    LDAG(fE0, W2f, 64, 64, true, 2 * obp, 0);
    LDAG(fE1, W2f, 64, 64, true, 2 * obp, 1);
    LDAG(fO0, W2f, 64, 64, true, 2 * obp + 1, 0);
    LDAG(fO1, W2f, 64, 64, true, 2 * obp + 1, 1);
    f32x4 bE = *(const f32x4*)(b2 + 32 * obp + 4 * g);
    f32x4 bO = *(const f32x4*)(b2 + 32 * obp + 16 + 4 * g);
#pragma unroll
    for (int pb = 0; pb < 4; pb++) {
      f32x4 aE = MFMA(fE0, h1[pb][0], bE, 0, 0, 0);
      aE = MFMA(fE1, h1[pb][1], aE, 0, 0, 0);
      f32x4 aO = MFMA(fO0, h1[pb][0], bO, 0, 0, 0);
      aO = MFMA(fO1, h1[pb][1], aO, 0, 0, 0);
      h2[pb][obp] = pack8(leaky4(aE), leaky4(aO));
    }
  }

  bf16x8 h3[4][8];
#pragma unroll
  for (int obp = 0; obp < 8; obp++) {
    f32x4 bE = *(const f32x4*)(b3 + 32 * obp + 4 * g);
    f32x4 bO = *(const f32x4*)(b3 + 32 * obp + 16 + 4 * g);
    f32x4 aE[4], aO[4];
#pragma unroll
    for (int pb = 0; pb < 4; pb++) { aE[pb] = bE; aO[pb] = bO; }
#pragma unroll
    for (int ks = 0; ks < 4; ks++) {
      bf16x8 fE, fO;
      LDAG(fE, W3f, 128, 128, true, 2 * obp, ks);
      LDAG(fO, W3f, 128, 128, true, 2 * obp + 1, ks);
#pragma unroll
      for (int pb = 0; pb < 4; pb++) {
        aE[pb] = MFMA(fE, h2[pb][ks], aE[pb], 0, 0, 0);
        aO[pb] = MFMA(fO, h2[pb][ks], aO[pb], 0, 0, 0);
      }
    }
#pragma unroll
    for (int pb = 0; pb < 4; pb++)
      h3[pb][obp] = pack8(leaky4(aE[pb]), leaky4(aO[pb]));
  }

  f32x4 zp[4];
#pragma unroll
  for (int pb = 0; pb < 4; pb++) zp[pb] = f32x4{0.f, 0.f, 0.f, 0.f};

  for (int ob = 0; ob < 32; ob++) {
    f32x4 bv = *(const f32x4*)(b4 + 16 * ob + 4 * g);
    f32x4 w5v = *(const f32x4*)(W5f + 16 * ob + 4 * g);
    f32x4 a[4];
#pragma unroll
    for (int pb = 0; pb < 4; pb++) a[pb] = bv;
#pragma unroll
    for (int ks = 0; ks < 8; ks++) {
      bf16x8 f4;
      LDAG(f4, W4f, 256, 256, true, ob, ks);
#pragma unroll
      for (int pb = 0; pb < 4; pb++) a[pb] = MFMA(f4, h3[pb][ks], a[pb], 0, 0, 0);
    }
#pragma unroll
    for (int pb = 0; pb < 4; pb++) {
      f32x4 lv = leaky4(a[pb]);
#pragma unroll
      for (int i = 0; i < 4; i++) zp[pb][i] = fmaf(lv[i], w5v[i], zp[pb][i]);
    }
  }

  float zb[4];
#pragma unroll
  for (int pb = 0; pb < 4; pb++) {
    float s = zp[pb][0] + zp[pb][1] + zp[pb][2] + zp[pb][3];
    s += __shfl_xor(s, 16);
    s += __shfl_xor(s, 32);
    zb[pb] = s;
  }
  float zsel = (g == 0) ? zb[0] : (g == 1) ? zb[1] : (g == 2) ? zb[2] : zb[3];
  float z = zsel + b5[0];
  float lab = lbl[px0 + lane];
  float w = fmaxf(z, 0.f) - z * lab + log1pf(expf(-fabsf(z)));
#pragma unroll
  for (int m = 1; m <= 32; m <<= 1) w += __shfl_xor(w, m);
  if (lane == 0) zs[wave] = w;
  __syncthreads();
  if (t == 0)
    atomicAdd(out, (zs[0] + zs[1] + zs[2] + zs[3]) * (1.f / (float)NPIX));
}

extern "C" void kernel_launch(void* const* d_in, const int* in_sizes, int n_in,
                              void* d_out, int out_size, void* d_ws, size_t ws_size,
                              hipStream_t stream) {
  const float* x   = (const float*)d_in[0];
  const float* lbl = (const float*)d_in[1];
  const float* W1  = (const float*)d_in[2];
  const float* b1  = (const float*)d_in[3];
  const float* W2  = (const float*)d_in[4];
  const float* b2  = (const float*)d_in[5];
  const float* W3  = (const float*)d_in[6];
  const float* b3  = (const float*)d_in[7];
  const float* W4  = (const float*)d_in[8];
  const float* b4  = (const float*)d_in[9];
  const float* W5  = (const float*)d_in[10];
  const float* b5  = (const float*)d_in[11];
  float* out = (float*)d_out;

  hipMemsetAsync(d_out, 0, sizeof(float), stream);

  bool pre = ws_size >= (size_t)WTOT * sizeof(unsigned short);
  if (pre) {
    unsigned short* wbp = (unsigned short*)d_ws;
    wconv_kernel<<<(WTOT + 255) / 256, 256, 0, stream>>>(W1, W2, W3, W4, wbp);
    disc_lds<<<NPIX / 256, 256, 0, stream>>>(x, lbl, wbp, b1, b2, b3, b4, W5, b5, out);
  } else {
    disc_fb<<<NPIX / 256, 256, 0, stream>>>(x, lbl, W1, b1, W2, b2, W3, b3, W4, b4,
                                            W5, b5, out);
  }
}

// Round 9
// 191.020 us; speedup vs baseline: 1.1522x; 1.1522x over previous
//
#include <hip/hip_runtime.h>

// get_fc_pix_discriminator_1x1_solo: fused 5-layer per-pixel MLP + BCE mean.
// B=4, C=19, H=256, W=512 -> 524288 px. dims 19->64->128->256->512->1.
// R9: register diet for true 2 waves/SIMD. Evidence from R4-R8: min-waves>=2
// makes the allocator split the 256-reg budget 128 arch + 128 acc and SPILL
// if arch-live > 128; min-waves=1 relaxes to the 512 budget -> 1 wave/SIMD
// forever (R7/R8 stuck at 11.4% occupancy). Fix structurally: 32 px/wave
// (pb=2) halves activation registers (h3: 128->64 arch) so arch-live ~120
// fits the 128 cap -> waves_per_eu(2,2) with zero spill -> 2 WGs/CU, barrier
// drains cross-hidden. WG = 128 px, grid 4096; weight re-read doubles but is
// L2/L3-resident (HBM FETCH unchanged).

#define HW_ 131072      // 256*512 = 2^17
#define NPIX 524288

using bf16x8 = __attribute__((ext_vector_type(8))) short;
using f32x4  = __attribute__((ext_vector_type(4))) float;

#define MFMA __builtin_amdgcn_mfma_f32_16x16x32_bf16

__device__ __forceinline__ unsigned short f2bf(float f) {
  unsigned u = __builtin_bit_cast(unsigned, f);
  u += 0x7FFFu + ((u >> 16) & 1u);   // round-to-nearest-even
  return (unsigned short)(u >> 16);
}

// sigma^-1: k-slot -> source feature index (within 32-chunks)
__device__ __forceinline__ int kinv(int k) {
  return ((k >> 5) << 5) + (((k >> 2) & 1) << 4) + (((k >> 3) & 3) << 2) + (k & 3);
}

// ---- weight bf16 pre-conversion into MFMA A-fragment order ----------------
// layer frag space: [ob][ks][lane][j];  o = ob*16+(lane&15),
// k = ks*32+(lane>>4)*8+j, feature f = PERM ? kinv(k) : k (0 if f>=K0).
// elem offset = ((ob*KS+ks)<<9) + lane*8  -> 1KB coalesced frag per wave.
#define OW1 0
#define OW2 2048
#define OW3 10240
#define OW4 43008
#define WTOT 174080

template <int K0, int KP, bool PERM>
__device__ __forceinline__ void conv_layer(const float* __restrict__ W,
                                           unsigned short* __restrict__ out,
                                           int i) {
  int r9 = i & 511;
  int lane = r9 >> 3, j = r9 & 7;
  int frag = i >> 9;               // = ob*KS + ks
  constexpr int KS = KP / 32;
  int ob = frag / KS, ks = frag - ob * KS;
  int o = ob * 16 + (lane & 15);
  int k = ks * 32 + ((lane >> 4) << 3) + j;
  int f = PERM ? kinv(k) : k;
  out[i] = f2bf(f < K0 ? W[o * K0 + f] : 0.f);
}

__global__ void wconv_kernel(const float* __restrict__ W1, const float* __restrict__ W2,
                             const float* __restrict__ W3, const float* __restrict__ W4,
                             unsigned short* __restrict__ wb) {
  int i = blockIdx.x * 256 + threadIdx.x;
  if (i < OW2) {
    conv_layer<19, 32, false>(W1, wb + OW1, i - OW1);
  } else if (i < OW3) {
    conv_layer<64, 64, true>(W2, wb + OW2, i - OW2);
  } else if (i < OW4) {
    conv_layer<128, 128, true>(W3, wb + OW3, i - OW3);
  } else if (i < WTOT) {
    conv_layer<256, 256, true>(W4, wb + OW4, i - OW4);
  }
}

__device__ __forceinline__ f32x4 leaky4(f32x4 v) {
  f32x4 r;
#pragma unroll
  for (int i = 0; i < 4; i++) r[i] = fmaxf(v[i], 0.2f * v[i]);
  return r;
}

// f32 pair -> packed bf16x2 (RNE), single HW instruction (no builtin; T12)
__device__ __forceinline__ unsigned cvtpk(float lo, float hi) {
  unsigned r;
  asm("v_cvt_pk_bf16_f32 %0, %1, %2" : "=v"(r) : "v"(lo), "v"(hi));
  return r;
}
__device__ __forceinline__ bf16x8 pack8(f32x4 e, f32x4 o) {
  union { unsigned u[4]; bf16x8 v; } r;
  r.u[0] = cvtpk(e[0], e[1]);
  r.u[1] = cvtpk(e[2], e[3]);
  r.u[2] = cvtpk(o[0], o[1]);
  r.u[3] = cvtpk(o[2], o[3]);
  return r.v;
}

// ---- async global -> LDS staging (16B/lane, identity layout) --------------
__device__ __forceinline__ void gl16(const unsigned char* g, unsigned char* l) {
  __builtin_amdgcn_global_load_lds(
      (const __attribute__((address_space(1))) unsigned int*)(const void*)g,
      (__attribute__((address_space(3))) unsigned int*)(void*)l, 16, 0, 0);
}
// NB 4KB blocks: global src per-lane (base + t*16), LDS dest wave-uniform
// (base + wave*1024); HW writes lane i at dest + i*16 -> identity copy.
template <int NB>
__device__ __forceinline__ void stage(const unsigned char* __restrict__ g,
                                      unsigned char* l, int t) {
  int wbase = (t >> 6) << 10;
  int lbase = (t & 63) << 4;
#pragma unroll
  for (int i = 0; i < NB; i++)
    gl16(g + i * 4096 + wbase + lbase, l + i * 4096 + wbase);
}

// frag read from LDS chunk: local frag lf, lane-linear 16B (conflict-free)
#define LDF(bufp, lf) (*(const bf16x8*)((bufp) + ((lf) << 10) + (lane << 4)))

__global__ __launch_bounds__(256) __attribute__((amdgpu_waves_per_eu(2, 2)))
void disc_lds(const float* __restrict__ x, const float* __restrict__ lbl,
              const unsigned short* __restrict__ wb,
              const float* __restrict__ b1, const float* __restrict__ b2,
              const float* __restrict__ b3, const float* __restrict__ b4,
              const float* __restrict__ W5f, const float* __restrict__ b5,
              float* __restrict__ out) {
  __shared__ __align__(16) unsigned char sb0[32768];
  __shared__ __align__(16) unsigned char sb1[32768];
  // total LDS = 65536 B exactly; final reduction reuses sb0's bytes.

  int t = threadIdx.x;
  int wave = t >> 6, lane = t & 63;
  int g = lane >> 4, li = lane & 15;
  long px0 = ((long)blockIdx.x * 4 + wave) * 32;   // 32 px per wave
  int b = (int)(px0 >> 17);
  int hw0 = (int)(px0 & (HW_ - 1));
  const unsigned char* wb8 = (const unsigned char*)wb;

  // c0 = W1+W2 (20480 B) -> sb0
  stage<5>(wb8, sb0, t);
  __syncthreads();

  // c1 = W3 frags 0-31 -> sb1 (in flight across x-load + L1 + L2)
  stage<8>(wb8 + 20480, sb1, t);

  // ---- x -> B-frags (k = input channel c; c>=19 zero) ---------------------
  bf16x8 xb[2];
#pragma unroll
  for (int pb = 0; pb < 2; pb++) {
    const float* xp = x + (((long)b * 19) << 17) + hw0 + pb * 16 + li;
    bf16x8 v;
#pragma unroll
    for (int j = 0; j < 8; j++) {
      int c = 8 * g + j;
      float f = (c < 19) ? xp[(long)c << 17] : 0.f;
      v[j] = (short)f2bf(f);
    }
    xb[pb] = v;
  }

  // ---- L1: 19->64, frags 0..3 in sb0 --------------------------------------
  bf16x8 h1[2][2];
#pragma unroll
  for (int obp = 0; obp < 2; obp++) {
    bf16x8 fE = LDF(sb0, 2 * obp);
    bf16x8 fO = LDF(sb0, 2 * obp + 1);
    f32x4 bE = *(const f32x4*)(b1 + 32 * obp + 4 * g);
    f32x4 bO = *(const f32x4*)(b1 + 32 * obp + 16 + 4 * g);
#pragma unroll
    for (int pb = 0; pb < 2; pb++) {
      f32x4 aE = MFMA(fE, xb[pb], bE, 0, 0, 0);
      f32x4 aO = MFMA(fO, xb[pb], bO, 0, 0, 0);
      h1[pb][obp] = pack8(leaky4(aE), leaky4(aO));
    }
  }

  // ---- L2: 64->128, frags 4 + ob*2 + ks in sb0 ----------------------------
  bf16x8 h2[2][4];
#pragma unroll
  for (int obp = 0; obp < 4; obp++) {
    bf16x8 fE0 = LDF(sb0, 4 + 4 * obp);
    bf16x8 fE1 = LDF(sb0, 4 + 4 * obp + 1);
    bf16x8 fO0 = LDF(sb0, 4 + 4 * obp + 2);
    bf16x8 fO1 = LDF(sb0, 4 + 4 * obp + 3);
    f32x4 bE = *(const f32x4*)(b2 + 32 * obp + 4 * g);
    f32x4 bO = *(const f32x4*)(b2 + 32 * obp + 16 + 4 * g);
#pragma unroll
    for (int pb = 0; pb < 2; pb++) {
      f32x4 aE = MFMA(fE0, h1[pb][0], bE, 0, 0, 0);
      aE = MFMA(fE1, h1[pb][1], aE, 0, 0, 0);
      f32x4 aO = MFMA(fO0, h1[pb][0], bO, 0, 0, 0);
      aO = MFMA(fO1, h1[pb][1], aO, 0, 0, 0);
      h2[pb][obp] = pack8(leaky4(aE), leaky4(aO));
    }
  }
  __syncthreads();           // drains c1

  // c2 = W3 frags 32-63 -> sb0 (in flight across L3 half 0)
  stage<8>(wb8 + 53248, sb0, t);

  // ---- L3 half 0: obs 0-7 from sb1 ----------------------------------------
  bf16x8 h3[2][8];
#pragma unroll
  for (int obp = 0; obp < 4; obp++) {
    int lfE = (2 * obp) * 4, lfO = (2 * obp + 1) * 4;
    f32x4 bE = *(const f32x4*)(b3 + 32 * obp + 4 * g);
    f32x4 bO = *(const f32x4*)(b3 + 32 * obp + 16 + 4 * g);
    f32x4 aE[2], aO[2];
#pragma unroll
    for (int pb = 0; pb < 2; pb++) { aE[pb] = bE; aO[pb] = bO; }
#pragma unroll
    for (int ks = 0; ks < 4; ks++) {
      bf16x8 fE = LDF(sb1, lfE + ks);
      bf16x8 fO = LDF(sb1, lfO + ks);
#pragma unroll
      for (int pb = 0; pb < 2; pb++) {
        aE[pb] = MFMA(fE, h2[pb][ks], aE[pb], 0, 0, 0);
        aO[pb] = MFMA(fO, h2[pb][ks], aO[pb], 0, 0, 0);
      }
    }
#pragma unroll
    for (int pb = 0; pb < 2; pb++)
      h3[pb][obp] = pack8(leaky4(aE[pb]), leaky4(aO[pb]));
  }
  __syncthreads();           // drains c2

  // c3 = W4 frags 0-31 -> sb1 (in flight across L3 half 1)
  stage<8>(wb8 + 86016, sb1, t);

  // ---- L3 half 1: obs 8-15 from sb0 ---------------------------------------
#pragma unroll
  for (int obp = 4; obp < 8; obp++) {
    int lfE = (2 * obp) * 4 - 32, lfO = (2 * obp + 1) * 4 - 32;
    f32x4 bE = *(const f32x4*)(b3 + 32 * obp + 4 * g);
    f32x4 bO = *(const f32x4*)(b3 + 32 * obp + 16 + 4 * g);
    f32x4 aE[2], aO[2];
#pragma unroll
    for (int pb = 0; pb < 2; pb++) { aE[pb] = bE; aO[pb] = bO; }
#pragma unroll
    for (int ks = 0; ks < 4; ks++) {
      bf16x8 fE = LDF(sb0, lfE + ks);
      bf16x8 fO = LDF(sb0, lfO + ks);
#pragma unroll
      for (int pb = 0; pb < 2; pb++) {
        aE[pb] = MFMA(fE, h2[pb][ks], aE[pb], 0, 0, 0);
        aO[pb] = MFMA(fO, h2[pb][ks], aO[pb], 0, 0, 0);
      }
    }
#pragma unroll
    for (int pb = 0; pb < 2; pb++)
      h3[pb][obp] = pack8(leaky4(aE[pb]), leaky4(aO[pb]));
  }
  __syncthreads();           // drains c3

  // ---- L4+L5 fused: 8 chunks x 4 obs, LDS ping-pong with async prefetch ---
  f32x4 zp[2];
#pragma unroll
  for (int pb = 0; pb < 2; pb++) zp[pb] = f32x4{0.f, 0.f, 0.f, 0.f};

#pragma unroll 1
  for (int j = 0; j < 8; j++) {
    const unsigned char* cur = (j & 1) ? sb0 : sb1;
    unsigned char* nxt = (j & 1) ? sb1 : sb0;
    if (j < 7) stage<8>(wb8 + 86016 + (j + 1) * 32768, nxt, t);
    for (int oo = 0; oo < 4; oo++) {
      int ob = 4 * j + oo;
      f32x4 bv = *(const f32x4*)(b4 + 16 * ob + 4 * g);
      f32x4 w5v = *(const f32x4*)(W5f + 16 * ob + 4 * g);
      f32x4 a[2];
#pragma unroll
      for (int pb = 0; pb < 2; pb++) a[pb] = bv;
#pragma unroll
      for (int ks = 0; ks < 8; ks++) {
        bf16x8 f4 = LDF(cur, oo * 8 + ks);
#pragma unroll
        for (int pb = 0; pb < 2; pb++) a[pb] = MFMA(f4, h3[pb][ks], a[pb], 0, 0, 0);
      }
#pragma unroll
      for (int pb = 0; pb < 2; pb++) {
        f32x4 lv = leaky4(a[pb]);
#pragma unroll
        for (int i = 0; i < 4; i++) zp[pb][i] = fmaf(lv[i], w5v[i], zp[pb][i]);
      }
    }
    __syncthreads();   // all waves done reading cur; prefetch into nxt drained
  }

  // ---- z per pixel + BCE + reduction (reuse sb0 bytes for 4 floats) -------
  float zb[2];
#pragma unroll
  for (int pb = 0; pb < 2; pb++) {
    float s = zp[pb][0] + zp[pb][1] + zp[pb][2] + zp[pb][3];
    s += __shfl_xor(s, 16);
    s += __shfl_xor(s, 32);
    zb[pb] = s;  // full z for px (pb,li), replicated across g
  }
  // lanes 0-15 -> pb0 px, lanes 16-31 -> pb1 px, lanes 32-63 idle
  float w = 0.f;
  if (lane < 32) {
    float z = ((lane & 16) ? zb[1] : zb[0]) + b5[0];
    float lab = lbl[px0 + lane];
    w = fmaxf(z, 0.f) - z * lab + log1pf(expf(-fabsf(z)));
  }
#pragma unroll
  for (int m = 1; m <= 32; m <<= 1) w += __shfl_xor(w, m);
  float* zsp = (float*)sb0;  // weights fully consumed after last barrier
  if (lane == 0) zsp[wave] = w;
  __syncthreads();
  if (t == 0)
    atomicAdd(out, (zsp[0] + zsp[1] + zsp[2] + zsp[3]) * (1.f / (float)NPIX));
}

// ---- fallback (ws too small): R5 register-chained kernel, direct gather ---
#define LDAG(dst, Wf, K0, KP, PERM, ob, ks)                                    \
  do {                                                                         \
    int o_ = (ob) * 16 + li;                                                   \
    for (int j_ = 0; j_ < 8; j_++) {                                           \
      int k_ = (ks) * 32 + (g << 3) + j_;                                      \
      int f_ = (PERM) ? kinv(k_) : k_;                                         \
      float v_ = f_ < (K0) ? (Wf)[o_ * (K0) + f_] : 0.f;                       \
      dst[j_] = (short)f2bf(v_);                                               \
    }                                                                          \
  } while (0)

__global__ __launch_bounds__(256, 1) void disc_fb(
    const float* __restrict__ x, const float* __restrict__ lbl,
    const float* __restrict__ W1f, const float* __restrict__ b1,
    const float* __restrict__ W2f, const float* __restrict__ b2,
    const float* __restrict__ W3f, const float* __restrict__ b3,
    const float* __restrict__ W4f, const float* __restrict__ b4,
    const float* __restrict__ W5f, const float* __restrict__ b5,
    float* __restrict__ out) {
  __shared__ float zs[4];
  int t = threadIdx.x;
  int wave = t >> 6, lane = t & 63;
  int g = lane >> 4, li = lane & 15;
  long px0 = ((long)blockIdx.x * 4 + wave) * 64;
  int b = (int)(px0 >> 17);
  int hw0 = (int)(px0 & (HW_ - 1));

  bf16x8 xb[4];
#pragma unroll
  for (int pb = 0; pb < 4; pb++) {
    const float* xp = x + (((long)b * 19) << 17) + hw0 + pb * 16 + li;
    bf16x8 v;
#pragma unroll
    for (int j = 0; j < 8; j++) {
      int c = 8 * g + j;
      float f = (c < 19) ? xp[(long)c << 17] : 0.f;
      v[j] = (short)f2bf(f);
    }
    xb[pb] = v;
  }

  bf16x8 h1[4][2];
#pragma unroll
  for (int obp = 0; obp < 2; obp++) {
    bf16x8 fE, fO;
    LDAG(fE, W1f, 19, 32, false, 2 * obp, 0);
    LDAG(fO, W1f, 19, 32, false, 2 * obp + 1, 0);
    f32x4 bE = *(const f32x4*)(b1 + 32 * obp + 4 * g);
    f32x4 bO = *(const f32x4*)(b1 + 32 * obp + 16 + 4 * g);
#pragma unroll
    for (int pb = 0; pb < 4; pb++) {
      f32x4 aE = MFMA(fE, xb[pb], bE, 0, 0, 0);
      f32x4 aO = MFMA(fO, xb[pb], bO, 0, 0, 0);
      h1[pb][obp] = pack8(leaky4(aE), leaky4(aO));
    }
  }

  bf16x8 h2[4][4];
#pragma unroll
  for (int obp = 0; obp < 4; obp++) {
    bf16x8 fE0, fE1, fO0, fO1;
    LDAG(fE0, W2f, 64, 64, true, 2 * obp, 0);
    LDAG(fE1, W2f, 64, 64, true, 2 * obp, 1);
    LDAG(fO0, W2f, 64, 64, true, 2 * obp + 1, 0);
    LDAG(fO1, W2f, 64, 64, true, 2 * obp + 1, 1);
    f32x4 bE = *(const f32x4*)(b2 + 32 * obp + 4 * g);
    f32x4 bO = *(const f32x4*)(b2 + 32 * obp + 16 + 4 * g);
#pragma unroll
    for (int pb = 0; pb < 4; pb++) {
      f32x4 aE = MFMA(fE0, h1[pb][0], bE, 0, 0, 0);
      aE = MFMA(fE1, h1[pb][1], aE, 0, 0, 0);
      f32x4 aO = MFMA(fO0, h1[pb][0], bO, 0, 0, 0);
      aO = MFMA(fO1, h1[pb][1], aO, 0, 0, 0);
      h2[pb][obp] = pack8(leaky4(aE), leaky4(aO));
    }
  }

  bf16x8 h3[4][8];
#pragma unroll
  for (int obp = 0; obp < 8; obp++) {
    f32x4 bE = *(const f32x4*)(b3 + 32 * obp + 4 * g);
    f32x4 bO = *(const f32x4*)(b3 + 32 * obp + 16 + 4 * g);
    f32x4 aE[4], aO[4];
#pragma unroll
    for (int pb = 0; pb < 4; pb++) { aE[pb] = bE; aO[pb] = bO; }
#pragma unroll
    for (int ks = 0; ks < 4; ks++) {
      bf16x8 fE, fO;
      LDAG(fE, W3f, 128, 128, true, 2 * obp, ks);
      LDAG(fO, W3f, 128, 128, true, 2 * obp + 1, ks);
#pragma unroll
      for (int pb = 0; pb < 4; pb++) {
        aE[pb] = MFMA(fE, h2[pb][ks], aE[pb], 0, 0, 0);
        aO[pb] = MFMA(fO, h2[pb][ks], aO[pb], 0, 0, 0);
      }
    }
#pragma unroll
    for (int pb = 0; pb < 4; pb++)
      h3[pb][obp] = pack8(leaky4(aE[pb]), leaky4(aO[pb]));
  }

  f32x4 zp[4];
#pragma unroll
  for (int pb = 0; pb < 4; pb++) zp[pb] = f32x4{0.f, 0.f, 0.f, 0.f};

  for (int ob = 0; ob < 32; ob++) {
    f32x4 bv = *(const f32x4*)(b4 + 16 * ob + 4 * g);
    f32x4 w5v = *(const f32x4*)(W5f + 16 * ob + 4 * g);
    f32x4 a[4];
#pragma unroll
    for (int pb = 0; pb < 4; pb++) a[pb] = bv;
#pragma unroll
    for (int ks = 0; ks < 8; ks++) {
      bf16x8 f4;
      LDAG(f4, W4f, 256, 256, true, ob, ks);
#pragma unroll
      for (int pb = 0; pb < 4; pb++) a[pb] = MFMA(f4, h3[pb][ks], a[pb], 0, 0, 0);
    }
#pragma unroll
    for (int pb = 0; pb < 4; pb++) {
      f32x4 lv = leaky4(a[pb]);
#pragma unroll
      for (int i = 0; i < 4; i++) zp[pb][i] = fmaf(lv[i], w5v[i], zp[pb][i]);
    }
  }

  float zb[4];
#pragma unroll
  for (int pb = 0; pb < 4; pb++) {
    float s = zp[pb][0] + zp[pb][1] + zp[pb][2] + zp[pb][3];
    s += __shfl_xor(s, 16);
    s += __shfl_xor(s, 32);
    zb[pb] = s;
  }
  float zsel = (g == 0) ? zb[0] : (g == 1) ? zb[1] : (g == 2) ? zb[2] : zb[3];
  float z = zsel + b5[0];
  float lab = lbl[px0 + lane];
  float w = fmaxf(z, 0.f) - z * lab + log1pf(expf(-fabsf(z)));
#pragma unroll
  for (int m = 1; m <= 32; m <<= 1) w += __shfl_xor(w, m);
  if (lane == 0) zs[wave] = w;
  __syncthreads();
  if (t == 0)
    atomicAdd(out, (zs[0] + zs[1] + zs[2] + zs[3]) * (1.f / (float)NPIX));
}

extern "C" void kernel_launch(void* const* d_in, const int* in_sizes, int n_in,
                              void* d_out, int out_size, void* d_ws, size_t ws_size,
                              hipStream_t stream) {
  const float* x   = (const float*)d_in[0];
  const float* lbl = (const float*)d_in[1];
  const float* W1  = (const float*)d_in[2];
  const float* b1  = (const float*)d_in[3];
  const float* W2  = (const float*)d_in[4];
  const float* b2  = (const float*)d_in[5];
  const float* W3  = (const float*)d_in[6];
  const float* b3  = (const float*)d_in[7];
  const float* W4  = (const float*)d_in[8];
  const float* b4  = (const float*)d_in[9];
  const float* W5  = (const float*)d_in[10];
  const float* b5  = (const float*)d_in[11];
  float* out = (float*)d_out;

  hipMemsetAsync(d_out, 0, sizeof(float), stream);

  bool pre = ws_size >= (size_t)WTOT * sizeof(unsigned short);
  if (pre) {
    unsigned short* wbp = (unsigned short*)d_ws;
    wconv_kernel<<<(WTOT + 255) / 256, 256, 0, stream>>>(W1, W2, W3, W4, wbp);
    disc_lds<<<NPIX / 128, 256, 0, stream>>>(x, lbl, wbp, b1, b2, b3, b4, W5, b5, out);
  } else {
    disc_fb<<<NPIX / 256, 256, 0, stream>>>(x, lbl, W1, b1, W2, b2, W3, b3, W4, b4,
                                            W5, b5, out);
  }
}